// Round 2
// baseline (523.824 us; speedup 1.0000x reference)
//
#include <hip/hip_runtime.h>
#include <stdint.h>

typedef unsigned int   u32;
typedef unsigned short u16;

#define HW 16384            // 128*128

typedef __attribute__((ext_vector_type(8)))  _Float16 half8;
typedef __attribute__((ext_vector_type(16))) float    f32x16;

__device__ __forceinline__ float sigm(float x) { return 1.f / (1.f + __expf(-x)); }

// ---------------------------------------------------------------------------
// R8: latency-hiding pass.
//   R7 post-mortem: VGPR=48, VALUBusy 18.6%, MfmaUtil 3%, HBM 16% -> nothing
//   saturated = latency-bound. Compiler allocated too few regs to pipeline the
//   GEMM loads (unroll-2 -> 8 serialized ~500cy vmcnt stalls/wave), and the
//   epilogue's msg/xph chains (60 strided loads + sigmoids) sat AFTER the
//   barrier despite not needing sacc.
//   Fix 1: explicit depth-3 software pipeline in the GEMM K-loop (named reg
//          buffers, compile-time indices; target VGPR ~100-128 @ 4 waves/SIMD).
//   Fix 2: hoist all sacc-independent epilogue work pre-barrier (msg, xph,
//          gates, xfa=W@xv [relu commutes with att>0], tta, sua). Post-barrier
//          is only tt/dp/att/update (~550 FMA + 12 LDS reads).
// ---------------------------------------------------------------------------

// Prep: pack padded 32x256 weight matrix (rows 0..19 = pdp_w1 hf-cols,
// row 20 = dU_aw[0:256], row 21 = dL_aw[0:256], rows 22..31 = 0) into
// lane-ordered split-f16 fragments: apack[s*512 + l*8 + j], s=K-step.
__global__ __launch_bounds__(256) void prep_apack(
    const float* __restrict__ pdp_w1, const float* __restrict__ dU_aw,
    const float* __restrict__ dL_aw, _Float16* __restrict__ apack)
{
    int idx = blockIdx.x * 256 + threadIdx.x;      // [0, 8192)
    int s = idx >> 9, rem = idx & 511, l = rem >> 3, j = rem & 7;
    int o = l & 31, kh = l >> 5;
    int k = s * 16 + kh * 8 + j;
    float wv = 0.f;
    if (o < 20)       wv = pdp_w1[o * 276 + k];
    else if (o == 20) wv = dU_aw[k];
    else if (o == 21) wv = dL_aw[k];
    _Float16 h = (_Float16)wv;
    apack[idx]        = h;                          // A_hi
    apack[8192 + idx] = (_Float16)(wv - (float)h);  // A_lo (residual)
}

#define GLOAD(S, XB, AH, AL) do {                                   \
    AH = ahp[(S) * 64]; AL = alp[(S) * 64];                         \
    const float* bs_ = bp + (size_t)(S) * 16 * HW;                  \
    _Pragma("unroll")                                               \
    for (int j_ = 0; j_ < 8; ++j_) XB[j_] = bs_[(size_t)j_ * HW];   \
} while (0)

#define GCOMP(XB, AH, AL) do {                                      \
    half8 Bh_, Bl_;                                                 \
    _Pragma("unroll")                                               \
    for (int j_ = 0; j_ < 8; ++j_) {                                \
        _Float16 h_ = (_Float16)XB[j_];                             \
        Bh_[j_] = h_;                                               \
        Bl_[j_] = (_Float16)(XB[j_] - (float)h_);                   \
    }                                                               \
    acc = __builtin_amdgcn_mfma_f32_32x32x16_f16(AH, Bh_, acc, 0, 0, 0); \
    acc = __builtin_amdgcn_mfma_f32_32x32x16_f16(AH, Bl_, acc, 0, 0, 0); \
    acc = __builtin_amdgcn_mfma_f32_32x32x16_f16(AL, Bh_, acc, 0, 0, 0); \
} while (0)

__global__ __launch_bounds__(256, 4) void half_graph_fused(
    const float* __restrict__ hf,  const float* __restrict__ xhu, const float* __restrict__ xhl,
    const float* __restrict__ xfg, const float* __restrict__ xpg,
    const float* __restrict__ pdp_w1, const float* __restrict__ pdp_w2,
    const float* __restrict__ att_w,  const float* __restrict__ att_b,
    const float* __restrict__ cU_aw, const float* __restrict__ cU_ab, const float* __restrict__ cU_w,
    const float* __restrict__ cL_aw, const float* __restrict__ cL_ab, const float* __restrict__ cL_w,
    const float* __restrict__ dU_aw, const float* __restrict__ dU_ab, const float* __restrict__ dU_w,
    const float* __restrict__ dL_aw, const float* __restrict__ dL_ab, const float* __restrict__ dL_w,
    const float* __restrict__ uU_gw, const float* __restrict__ uU_gb, const float* __restrict__ uU_cw,
    const float* __restrict__ uL_gw, const float* __restrict__ uL_gb, const float* __restrict__ uL_cw,
    const _Float16* __restrict__ apack,
    float* __restrict__ out)
{
    const int tid    = threadIdx.x;
    const int pxbase = blockIdx.x * 128;     // 128 px/block, same image (128 | 16384)
    const int n      = pxbase >> 14;
    const int hwbase = pxbase & 16383;

    __shared__ float sacc[22][128];          // GEMM rows x block-pixels (11.3 KB)

    // ---------------- GEMM phase: each wave = one 32px x 32row D tile --------
    {
        const int l   = tid & 63;
        const int w   = tid >> 6;            // wave -> pixel sub-tile
        const int col = l & 31;              // pixel column within tile
        const int kh  = l >> 5;              // k-half (upper lanes take k+8)
        const float* bp = hf + ((size_t)n * 256 + kh * 8) * HW + (hwbase + w * 32 + col);
        const half8* ahp = (const half8*)apack + l;          // [16 steps][64 lanes]
        const half8* alp = (const half8*)apack + 1024 + l;
        f32x16 acc = {};

        // depth-3 software pipeline: load step s+3 while computing step s
        float x0[8], x1[8], x2[8];
        half8 Ah0, Al0, Ah1, Al1, Ah2, Al2;
        GLOAD(0, x0, Ah0, Al0);
        GLOAD(1, x1, Ah1, Al1);
        GLOAD(2, x2, Ah2, Al2);
        GCOMP(x0, Ah0, Al0); GLOAD(3,  x0, Ah0, Al0);
        GCOMP(x1, Ah1, Al1); GLOAD(4,  x1, Ah1, Al1);
        GCOMP(x2, Ah2, Al2); GLOAD(5,  x2, Ah2, Al2);
        GCOMP(x0, Ah0, Al0); GLOAD(6,  x0, Ah0, Al0);
        GCOMP(x1, Ah1, Al1); GLOAD(7,  x1, Ah1, Al1);
        GCOMP(x2, Ah2, Al2); GLOAD(8,  x2, Ah2, Al2);
        GCOMP(x0, Ah0, Al0); GLOAD(9,  x0, Ah0, Al0);
        GCOMP(x1, Ah1, Al1); GLOAD(10, x1, Ah1, Al1);
        GCOMP(x2, Ah2, Al2); GLOAD(11, x2, Ah2, Al2);
        GCOMP(x0, Ah0, Al0); GLOAD(12, x0, Ah0, Al0);
        GCOMP(x1, Ah1, Al1); GLOAD(13, x1, Ah1, Al1);
        GCOMP(x2, Ah2, Al2); GLOAD(14, x2, Ah2, Al2);
        GCOMP(x0, Ah0, Al0); GLOAD(15, x0, Ah0, Al0);
        GCOMP(x1, Ah1, Al1);
        GCOMP(x2, Ah2, Al2);
        GCOMP(x0, Ah0, Al0);

        // D -> LDS (rows >= 22 are pad). bank = col&31 -> 2-way across wave = free.
        const int ccol = w * 32 + col;
        #pragma unroll
        for (int reg = 0; reg < 12; ++reg) {
            const int r = (reg & 3) + 8 * (reg >> 2) + 4 * kh;
            if (r < 22) sacc[r][ccol] = acc[reg];
        }
    }

    // ============ pre-barrier epilogue: everything sacc-independent =========
    const int q    = tid & 127;              // pixel within block
    const int role = tid >> 7;               // waves 0-1: U half, waves 2-3: L half
    const int hw   = hwbase + q;
    const int vb   = n * 10 * HW + hw;

    float xu[10], xl[10], xv[10];
    #pragma unroll
    for (int i = 0; i < 10; ++i) xu[i] = xhu[vb + i * HW];
    #pragma unroll
    for (int i = 0; i < 10; ++i) xl[i] = xhl[vb + i * HW];
    #pragma unroll
    for (int i = 0; i < 10; ++i) xv[i] = xfg[vb + i * HW];

    // gates
    float au_s = att_b[0], al_s = att_b[1];
    #pragma unroll
    for (int i = 0; i < 10; ++i) {
        au_s = fmaf(att_w[i],      xu[i], au_s);
        al_s = fmaf(att_w[10 + i], xl[i], al_s);
    }
    const float au = sigm(au_s), al = sigm(al_s);

    float xph[10];   // relu(comp_w @ [xh, msg])
    float xfa[10];   // dec_w @ xv (att applied post-barrier)
    float tta[10];   // pdp_w1 tail cols @ [xu, xl]
    float sa;        // dec att partial (bias + xv + xh terms)

    if (role == 0) {
        float msg[10];
        #pragma unroll
        for (int i = 0; i < 10; ++i) msg[i] = 0.f;
        #pragma unroll
        for (int pp = 0; pp < 4; ++pp) {
            const float* xq = xpg + (size_t)(pp * 8 + n) * 10 * HW + hw;
            float v[10];
            #pragma unroll
            for (int i = 0; i < 10; ++i) v[i] = xq[i * HW];
            float s = cU_ab[pp];
            #pragma unroll
            for (int i = 0; i < 10; ++i) s = fmaf(cU_aw[pp * 10 + i], v[i], s);
            float ca = sigm(s);
            #pragma unroll
            for (int i = 0; i < 10; ++i) msg[i] = fmaf(ca, v[i], msg[i]);
        }
        #pragma unroll
        for (int o = 0; o < 10; ++o) {
            float s = 0.f;
            #pragma unroll
            for (int i = 0; i < 10; ++i) s = fmaf(cU_w[o * 20 + i],      xu[i],  s);
            #pragma unroll
            for (int i = 0; i < 10; ++i) s = fmaf(cU_w[o * 20 + 10 + i], msg[i], s);
            xph[o] = fmaxf(s, 0.f);
        }
        #pragma unroll
        for (int o = 0; o < 10; ++o) {
            float a = 0.f;
            #pragma unroll
            for (int i = 0; i < 10; ++i) a = fmaf(dU_w[o * 10 + i], xv[i], a);
            xfa[o] = a;
        }
        #pragma unroll
        for (int o = 0; o < 10; ++o) {
            const float* wr = pdp_w1 + (10 + o) * 276;
            float s = 0.f;
            #pragma unroll
            for (int i = 0; i < 10; ++i) s = fmaf(wr[256 + i], xu[i], s);
            #pragma unroll
            for (int i = 0; i < 10; ++i) s = fmaf(wr[266 + i], xl[i], s);
            tta[o] = s;
        }
        float su = dU_ab[0];
        #pragma unroll
        for (int i = 0; i < 10; ++i) su = fmaf(dU_aw[256 + i], xv[i], su);
        #pragma unroll
        for (int i = 0; i < 10; ++i) su = fmaf(dU_aw[266 + i], xu[i], su);
        sa = su;
    } else {
        float msg[10];
        #pragma unroll
        for (int i = 0; i < 10; ++i) msg[i] = 0.f;
        #pragma unroll
        for (int pp = 0; pp < 2; ++pp) {
            const float* xq = xpg + (size_t)((pp + 4) * 8 + n) * 10 * HW + hw;
            float v[10];
            #pragma unroll
            for (int i = 0; i < 10; ++i) v[i] = xq[i * HW];
            float s = cL_ab[pp];
            #pragma unroll
            for (int i = 0; i < 10; ++i) s = fmaf(cL_aw[pp * 10 + i], v[i], s);
            float ca = sigm(s);
            #pragma unroll
            for (int i = 0; i < 10; ++i) msg[i] = fmaf(ca, v[i], msg[i]);
        }
        #pragma unroll
        for (int o = 0; o < 10; ++o) {
            float s = 0.f;
            #pragma unroll
            for (int i = 0; i < 10; ++i) s = fmaf(cL_w[o * 20 + i],      xl[i],  s);
            #pragma unroll
            for (int i = 0; i < 10; ++i) s = fmaf(cL_w[o * 20 + 10 + i], msg[i], s);
            xph[o] = fmaxf(s, 0.f);
        }
        #pragma unroll
        for (int o = 0; o < 10; ++o) {
            float a = 0.f;
            #pragma unroll
            for (int i = 0; i < 10; ++i) a = fmaf(dL_w[o * 10 + i], xv[i], a);
            xfa[o] = a;
        }
        #pragma unroll
        for (int o = 0; o < 10; ++o) {
            const float* wr = pdp_w1 + o * 276;
            float s = 0.f;
            #pragma unroll
            for (int i = 0; i < 10; ++i) s = fmaf(wr[256 + i], xu[i], s);
            #pragma unroll
            for (int i = 0; i < 10; ++i) s = fmaf(wr[266 + i], xl[i], s);
            tta[o] = s;
        }
        float sl = dL_ab[0];
        #pragma unroll
        for (int i = 0; i < 10; ++i) sl = fmaf(dL_aw[256 + i], xv[i], sl);
        #pragma unroll
        for (int i = 0; i < 10; ++i) sl = fmaf(dL_aw[266 + i], xl[i], sl);
        sa = sl;
    }

    __syncthreads();

    // ============ post-barrier: sacc-dependent tail =========================
    if (role == 0) {
        float tt[10];
        #pragma unroll
        for (int o = 0; o < 10; ++o) tt[o] = fmaxf(sacc[10 + o][q] + tta[o], 0.f);
        float dpl[10];
        #pragma unroll
        for (int o = 0; o < 10; ++o) {
            float s = 0.f;
            #pragma unroll
            for (int i = 0; i < 10; ++i) s = fmaf(pdp_w2[(10 + o) * 10 + i], tt[i], s);
            dpl[o] = fmaxf(s, 0.f);
        }
        const float attU = sigm(sacc[20][q] + sa);
        float m[10];
        #pragma unroll
        for (int o = 0; o < 10; ++o)
            m[o] = xph[o] + fmaf(dpl[o], al, xu[o] * au) + attU * fmaxf(xfa[o], 0.f);
        #pragma unroll
        for (int o = 0; o < 10; ++o) {
            float gs = uU_gb[o], cs = 0.f;
            #pragma unroll
            for (int i = 0; i < 10; ++i) {
                gs = fmaf(uU_gw[o * 20 + i], xu[i], gs);
                cs = fmaf(uU_cw[o * 20 + i], xu[i], cs);
            }
            #pragma unroll
            for (int i = 0; i < 10; ++i) {
                gs = fmaf(uU_gw[o * 20 + 10 + i], m[i], gs);
                cs = fmaf(uU_cw[o * 20 + 10 + i], m[i], cs);
            }
            float g = sigm(gs), cd = fmaxf(cs, 0.f);
            out[vb + o * HW] = xu[o] * (1.f - g) + cd * g;
        }
        out[2621440 + n * HW + hw] = attU;
    } else {
        float tt[10];
        #pragma unroll
        for (int o = 0; o < 10; ++o) tt[o] = fmaxf(sacc[o][q] + tta[o], 0.f);
        float dpu[10];
        #pragma unroll
        for (int o = 0; o < 10; ++o) {
            float s = 0.f;
            #pragma unroll
            for (int i = 0; i < 10; ++i) s = fmaf(pdp_w2[o * 10 + i], tt[i], s);
            dpu[o] = fmaxf(s, 0.f);
        }
        const float attL = sigm(sacc[21][q] + sa);
        float m[10];
        #pragma unroll
        for (int o = 0; o < 10; ++o)
            m[o] = xph[o] + fmaf(dpu[o], au, xl[o] * al) + attL * fmaxf(xfa[o], 0.f);
        #pragma unroll
        for (int o = 0; o < 10; ++o) {
            float gs = uL_gb[o], cs = 0.f;
            #pragma unroll
            for (int i = 0; i < 10; ++i) {
                gs = fmaf(uL_gw[o * 20 + i], xl[i], gs);
                cs = fmaf(uL_cw[o * 20 + i], xl[i], cs);
            }
            #pragma unroll
            for (int i = 0; i < 10; ++i) {
                gs = fmaf(uL_gw[o * 20 + 10 + i], m[i], gs);
                cs = fmaf(uL_cw[o * 20 + 10 + i], m[i], cs);
            }
            float g = sigm(gs), cd = fmaxf(cs, 0.f);
            out[1310720 + vb + o * HW] = xl[o] * (1.f - g) + cd * g;
        }
        out[2752512 + n * HW + hw] = attL;
    }
}

extern "C" void kernel_launch(void* const* d_in, const int* in_sizes, int n_in,
                              void* d_out, int out_size, void* d_ws, size_t ws_size,
                              hipStream_t stream) {
    (void)in_sizes; (void)n_in; (void)out_size; (void)ws_size;
    const float* hf   = (const float*)d_in[0];
    const float* xhu  = (const float*)d_in[1];
    const float* xhl  = (const float*)d_in[2];
    const float* xfg  = (const float*)d_in[3];
    const float* xpg  = (const float*)d_in[4];
    const float* w1   = (const float*)d_in[5];
    const float* w2   = (const float*)d_in[6];
    const float* aw   = (const float*)d_in[7];
    const float* ab   = (const float*)d_in[8];
    const float* cUaw = (const float*)d_in[9];
    const float* cUab = (const float*)d_in[10];
    const float* cUw  = (const float*)d_in[11];
    const float* cLaw = (const float*)d_in[12];
    const float* cLab = (const float*)d_in[13];
    const float* cLw  = (const float*)d_in[14];
    const float* dUaw = (const float*)d_in[15];
    const float* dUab = (const float*)d_in[16];
    const float* dUw  = (const float*)d_in[17];
    const float* dLaw = (const float*)d_in[18];
    const float* dLab = (const float*)d_in[19];
    const float* dLw  = (const float*)d_in[20];
    const float* uUgw = (const float*)d_in[21];
    const float* uUgb = (const float*)d_in[22];
    const float* uUcw = (const float*)d_in[23];
    const float* uLgw = (const float*)d_in[24];
    const float* uLgb = (const float*)d_in[25];
    const float* uLcw = (const float*)d_in[26];

    _Float16* apack = (_Float16*)d_ws;       // 32 KB: [16][64][8] hi + lo

    hipLaunchKernelGGL(prep_apack, dim3(32), dim3(256), 0, stream,
                       w1, dUaw, dLaw, apack);
    hipLaunchKernelGGL(half_graph_fused, dim3(1024), dim3(256), 0, stream,
        hf, xhu, xhl, xfg, xpg, w1, w2, aw, ab,
        cUaw, cUab, cUw, cLaw, cLab, cLw,
        dUaw, dUab, dUw, dLaw, dLab, dLw,
        uUgw, uUgb, uUcw, uLgw, uLgb, uLcw,
        (const _Float16*)apack,
        (float*)d_out);
}

// Round 5
// 297.546 us; speedup vs baseline: 1.7605x; 1.7605x over previous
//
#include <hip/hip_runtime.h>
#include <stdint.h>

#define HW   16384          // 128*128
#define NPIX 131072         // 8 * HW

typedef __attribute__((ext_vector_type(8)))  _Float16 half8;
typedef __attribute__((ext_vector_type(16))) float    f32x16;

__device__ __forceinline__ float sigm(float x) { return 1.f / (1.f + __expf(-x)); }

// ---------------------------------------------------------------------------
// R11 == R10 resubmit (container failed twice, no counters, both R9+R10).
//   Fallback path is byte-identical to R7 (passed, 78.8us); split path audited
//   OOB-clean. R8's own timing showed 600-1100s npz pushes -> degraded infra
//   is the leading hypothesis for the failures. Pre-committed rule: a third
//   no-counter failure indicts the split path; R12 then submits pure R7.
//   Theory unchanged: R7 latency-bound (VALU 18.6%, MFMA 3%, HBM 16%,
//   grid-capped 16 waves/CU). Split kernels raise TLP; hf becomes a stream.
// ---------------------------------------------------------------------------

// Pack padded 32x256 weight matrix (rows 0..19 = pdp_w1 hf-cols, row 20 =
// dU_aw[0:256], row 21 = dL_aw[0:256], rows 22..31 = 0) into lane-ordered
// split-f16 fragments: apack[s*512 + l*8 + j], s = K-step of 16.
__global__ __launch_bounds__(256) void prep_apack(
    const float* __restrict__ pdp_w1, const float* __restrict__ dU_aw,
    const float* __restrict__ dL_aw, _Float16* __restrict__ apack)
{
    int idx = blockIdx.x * 256 + threadIdx.x;      // [0, 8192)
    int s = idx >> 9, rem = idx & 511, l = rem >> 3, j = rem & 7;
    int o = l & 31, kh = l >> 5;
    int k = s * 16 + kh * 8 + j;
    float wv = 0.f;
    if (o < 20)       wv = pdp_w1[o * 276 + k];
    else if (o == 20) wv = dU_aw[k];
    else if (o == 21) wv = dL_aw[k];
    _Float16 h = (_Float16)wv;
    apack[idx]        = h;                          // A_hi
    apack[8192 + idx] = (_Float16)(wv - (float)h);  // A_lo (residual)
}

// ========================== split path (ws >= 11.6MB) ======================
// GEMM: gout[r][p] = sum_k W[r][k] * hf[n][k][hw], r<22.
// Waves (0,1)=px tiles for K[0,128), waves (2,3)=px tiles for K[128,256).
// 64 px/block, grid 2048. f16-split: 3 mfma_32x32x16 per 16-chan step.
// C/D: col=lane&31, row=(reg&3)+8*(reg>>2)+4*(lane>>5)   [R7-verified]
__global__ __launch_bounds__(256, 6) void gemm22(
    const float* __restrict__ hf, const _Float16* __restrict__ apack,
    float* __restrict__ gout)
{
    const int tid    = threadIdx.x;
    const int l      = tid & 63, w = tid >> 6;
    const int pxbase = blockIdx.x * 64;          // 64 | 16384 -> single image
    const int n      = pxbase >> 14;
    const int hwbase = pxbase & 16383;
    const int ptile  = w & 1;                    // pixel sub-tile
    const int khalf  = w >> 1;                   // K half: 0 or 1
    const int col    = l & 31, kh = l >> 5;

    const float* bp = hf + ((size_t)(n * 256 + khalf * 128 + kh * 8)) * HW
                         + hwbase + ptile * 32 + col;
    const half8* ahp = (const half8*)apack + khalf * 512 + l;   // [8 steps][64]
    const half8* alp = ahp + 1024;

    f32x16 acc = {};
    #pragma unroll 2
    for (int s = 0; s < 8; ++s) {
        half8 Ah = ahp[s * 64];
        half8 Al = alp[s * 64];
        float x[8];
        #pragma unroll
        for (int j = 0; j < 8; ++j) x[j] = bp[(size_t)(s * 16 + j) * HW];
        half8 Bh, Bl;
        #pragma unroll
        for (int j = 0; j < 8; ++j) {
            _Float16 h = (_Float16)x[j];
            Bh[j] = h;
            Bl[j] = (_Float16)(x[j] - (float)h);
        }
        acc = __builtin_amdgcn_mfma_f32_32x32x16_f16(Ah, Bh, acc, 0, 0, 0);
        acc = __builtin_amdgcn_mfma_f32_32x32x16_f16(Ah, Bl, acc, 0, 0, 0);
        acc = __builtin_amdgcn_mfma_f32_32x32x16_f16(Al, Bh, acc, 0, 0, 0);
    }

    __shared__ float sacc[2][22][64];            // 11.3 KB
    const int ccol = ptile * 32 + col;
    #pragma unroll
    for (int reg = 0; reg < 12; ++reg) {
        const int r = (reg & 3) + 8 * (reg >> 2) + 4 * kh;
        if (r < 22) sacc[khalf][r][ccol] = acc[reg];
    }
    __syncthreads();

    for (int idx = tid; idx < 22 * 64; idx += 256) {   // combine K halves
        int r = idx >> 6, c = idx & 63;
        gout[(size_t)r * NPIX + pxbase + c] = sacc[0][r][c] + sacc[1][r][c];
    }
}

// Per-pixel tail. role = tid>>6 (wave-uniform): 0 = U half, 1 = L half.
__global__ __launch_bounds__(128, 6) void half_graph_epi(
    const float* __restrict__ gac,
    const float* __restrict__ xhu, const float* __restrict__ xhl,
    const float* __restrict__ xfg, const float* __restrict__ xpg,
    const float* __restrict__ pdp_w1, const float* __restrict__ pdp_w2,
    const float* __restrict__ att_w,  const float* __restrict__ att_b,
    const float* __restrict__ cU_aw, const float* __restrict__ cU_ab, const float* __restrict__ cU_w,
    const float* __restrict__ cL_aw, const float* __restrict__ cL_ab, const float* __restrict__ cL_w,
    const float* __restrict__ dU_aw, const float* __restrict__ dU_ab, const float* __restrict__ dU_w,
    const float* __restrict__ dL_aw, const float* __restrict__ dL_ab, const float* __restrict__ dL_w,
    const float* __restrict__ uU_gw, const float* __restrict__ uU_gb, const float* __restrict__ uU_cw,
    const float* __restrict__ uL_gw, const float* __restrict__ uL_gb, const float* __restrict__ uL_cw,
    float* __restrict__ out)
{
    const int tid  = threadIdx.x;
    const int q    = tid & 63;
    const int role = tid >> 6;                   // wave-uniform
    const int p    = blockIdx.x * 64 + q;
    const int n    = p >> 14, hw = p & 16383;
    const int vb   = n * 10 * HW + hw;
    const float* gr = gac + p;                   // row r at gr[r*NPIX]

    float xu[10], xl[10], xv[10];
    #pragma unroll
    for (int i = 0; i < 10; ++i) xu[i] = xhu[vb + i * HW];
    #pragma unroll
    for (int i = 0; i < 10; ++i) xl[i] = xhl[vb + i * HW];
    #pragma unroll
    for (int i = 0; i < 10; ++i) xv[i] = xfg[vb + i * HW];

    float au_s = att_b[0], al_s = att_b[1];
    #pragma unroll
    for (int i = 0; i < 10; ++i) {
        au_s = fmaf(att_w[i],      xu[i], au_s);
        al_s = fmaf(att_w[10 + i], xl[i], al_s);
    }
    const float au = sigm(au_s), al = sigm(al_s);

    if (role == 0) {
        float tt[10];
        #pragma unroll
        for (int o = 0; o < 10; ++o) {
            const float* wr = pdp_w1 + (10 + o) * 276;
            float s = gr[(size_t)(10 + o) * NPIX];
            #pragma unroll
            for (int i = 0; i < 10; ++i) s = fmaf(wr[256 + i], xu[i], s);
            #pragma unroll
            for (int i = 0; i < 10; ++i) s = fmaf(wr[266 + i], xl[i], s);
            tt[o] = fmaxf(s, 0.f);
        }
        float dpl[10];
        #pragma unroll
        for (int o = 0; o < 10; ++o) {
            float s = 0.f;
            #pragma unroll
            for (int i = 0; i < 10; ++i) s = fmaf(pdp_w2[(10 + o) * 10 + i], tt[i], s);
            dpl[o] = fmaxf(s, 0.f);
        }
        float su = gr[(size_t)20 * NPIX] + dU_ab[0];
        #pragma unroll
        for (int i = 0; i < 10; ++i) su = fmaf(dU_aw[256 + i], xv[i], su);
        #pragma unroll
        for (int i = 0; i < 10; ++i) su = fmaf(dU_aw[266 + i], xu[i], su);
        const float attU = sigm(su);
        float msg[10];
        #pragma unroll
        for (int i = 0; i < 10; ++i) msg[i] = 0.f;
        #pragma unroll
        for (int pp = 0; pp < 4; ++pp) {
            const float* xq = xpg + (size_t)(pp * 8 + n) * 10 * HW + hw;
            float v[10];
            #pragma unroll
            for (int i = 0; i < 10; ++i) v[i] = xq[i * HW];
            float s = cU_ab[pp];
            #pragma unroll
            for (int i = 0; i < 10; ++i) s = fmaf(cU_aw[pp * 10 + i], v[i], s);
            float ca = sigm(s);
            #pragma unroll
            for (int i = 0; i < 10; ++i) msg[i] = fmaf(ca, v[i], msg[i]);
        }
        float m[10];
        #pragma unroll
        for (int o = 0; o < 10; ++o) {
            float s = 0.f, a = 0.f;
            #pragma unroll
            for (int i = 0; i < 10; ++i) s = fmaf(cU_w[o * 20 + i],      xu[i],  s);
            #pragma unroll
            for (int i = 0; i < 10; ++i) s = fmaf(cU_w[o * 20 + 10 + i], msg[i], s);
            #pragma unroll
            for (int i = 0; i < 10; ++i) a = fmaf(dU_w[o * 10 + i], xv[i], a);
            m[o] = fmaxf(s, 0.f) + fmaf(dpl[o], al, xu[o] * au) + attU * fmaxf(a, 0.f);
        }
        #pragma unroll
        for (int o = 0; o < 10; ++o) {
            float gs = uU_gb[o], cs = 0.f;
            #pragma unroll
            for (int i = 0; i < 10; ++i) {
                gs = fmaf(uU_gw[o * 20 + i], xu[i], gs);
                cs = fmaf(uU_cw[o * 20 + i], xu[i], cs);
            }
            #pragma unroll
            for (int i = 0; i < 10; ++i) {
                gs = fmaf(uU_gw[o * 20 + 10 + i], m[i], gs);
                cs = fmaf(uU_cw[o * 20 + 10 + i], m[i], cs);
            }
            float g = sigm(gs), cd = fmaxf(cs, 0.f);
            out[vb + o * HW] = xu[o] * (1.f - g) + cd * g;
        }
        out[2621440 + n * HW + hw] = attU;
    } else {
        float tt[10];
        #pragma unroll
        for (int o = 0; o < 10; ++o) {
            const float* wr = pdp_w1 + o * 276;
            float s = gr[(size_t)o * NPIX];
            #pragma unroll
            for (int i = 0; i < 10; ++i) s = fmaf(wr[256 + i], xu[i], s);
            #pragma unroll
            for (int i = 0; i < 10; ++i) s = fmaf(wr[266 + i], xl[i], s);
            tt[o] = fmaxf(s, 0.f);
        }
        float dpu[10];
        #pragma unroll
        for (int o = 0; o < 10; ++o) {
            float s = 0.f;
            #pragma unroll
            for (int i = 0; i < 10; ++i) s = fmaf(pdp_w2[o * 10 + i], tt[i], s);
            dpu[o] = fmaxf(s, 0.f);
        }
        float sl = gr[(size_t)21 * NPIX] + dL_ab[0];
        #pragma unroll
        for (int i = 0; i < 10; ++i) sl = fmaf(dL_aw[256 + i], xv[i], sl);
        #pragma unroll
        for (int i = 0; i < 10; ++i) sl = fmaf(dL_aw[266 + i], xl[i], sl);
        const float attL = sigm(sl);
        float msg[10];
        #pragma unroll
        for (int i = 0; i < 10; ++i) msg[i] = 0.f;
        #pragma unroll
        for (int pp = 0; pp < 2; ++pp) {
            const float* xq = xpg + (size_t)((pp + 4) * 8 + n) * 10 * HW + hw;
            float v[10];
            #pragma unroll
            for (int i = 0; i < 10; ++i) v[i] = xq[i * HW];
            float s = cL_ab[pp];
            #pragma unroll
            for (int i = 0; i < 10; ++i) s = fmaf(cL_aw[pp * 10 + i], v[i], s);
            float ca = sigm(s);
            #pragma unroll
            for (int i = 0; i < 10; ++i) msg[i] = fmaf(ca, v[i], msg[i]);
        }
        float m[10];
        #pragma unroll
        for (int o = 0; o < 10; ++o) {
            float s = 0.f, a = 0.f;
            #pragma unroll
            for (int i = 0; i < 10; ++i) s = fmaf(cL_w[o * 20 + i],      xl[i],  s);
            #pragma unroll
            for (int i = 0; i < 10; ++i) s = fmaf(cL_w[o * 20 + 10 + i], msg[i], s);
            #pragma unroll
            for (int i = 0; i < 10; ++i) a = fmaf(dL_w[o * 10 + i], xv[i], a);
            m[o] = fmaxf(s, 0.f) + fmaf(dpu[o], au, xl[o] * al) + attL * fmaxf(a, 0.f);
        }
        #pragma unroll
        for (int o = 0; o < 10; ++o) {
            float gs = uL_gb[o], cs = 0.f;
            #pragma unroll
            for (int i = 0; i < 10; ++i) {
                gs = fmaf(uL_gw[o * 20 + i], xl[i], gs);
                cs = fmaf(uL_cw[o * 20 + i], xl[i], cs);
            }
            #pragma unroll
            for (int i = 0; i < 10; ++i) {
                gs = fmaf(uL_gw[o * 20 + 10 + i], m[i], gs);
                cs = fmaf(uL_cw[o * 20 + 10 + i], m[i], cs);
            }
            float g = sigm(gs), cd = fmaxf(cs, 0.f);
            out[1310720 + vb + o * HW] = xl[o] * (1.f - g) + cd * g;
        }
        out[2752512 + n * HW + hw] = attL;
    }
}

// ========================== fallback path (R7, proven 78.8us) ==============
__global__ __launch_bounds__(256, 4) void half_graph_fused(
    const float* __restrict__ hf,  const float* __restrict__ xhu, const float* __restrict__ xhl,
    const float* __restrict__ xfg, const float* __restrict__ xpg,
    const float* __restrict__ pdp_w1, const float* __restrict__ pdp_w2,
    const float* __restrict__ att_w,  const float* __restrict__ att_b,
    const float* __restrict__ cU_aw, const float* __restrict__ cU_ab, const float* __restrict__ cU_w,
    const float* __restrict__ cL_aw, const float* __restrict__ cL_ab, const float* __restrict__ cL_w,
    const float* __restrict__ dU_aw, const float* __restrict__ dU_ab, const float* __restrict__ dU_w,
    const float* __restrict__ dL_aw, const float* __restrict__ dL_ab, const float* __restrict__ dL_w,
    const float* __restrict__ uU_gw, const float* __restrict__ uU_gb, const float* __restrict__ uU_cw,
    const float* __restrict__ uL_gw, const float* __restrict__ uL_gb, const float* __restrict__ uL_cw,
    const _Float16* __restrict__ apack,
    float* __restrict__ out)
{
    const int tid    = threadIdx.x;
    const int pxbase = blockIdx.x * 128;
    const int n      = pxbase >> 14;
    const int hwbase = pxbase & 16383;

    __shared__ float sacc[22][128];

    {
        const int l   = tid & 63;
        const int w   = tid >> 6;
        const int col = l & 31;
        const int kh  = l >> 5;
        const float* bp = hf + ((size_t)n * 256 + kh * 8) * HW + (hwbase + w * 32 + col);
        const half8* ah  = (const half8*)apack;
        const half8* al8 = ah + 1024;
        f32x16 acc = {};
        #pragma unroll 2
        for (int s = 0; s < 16; ++s) {
            half8 A_h = ah[s * 64 + l];
            half8 A_l = al8[s * 64 + l];
            float x[8];
            #pragma unroll
            for (int j = 0; j < 8; ++j) x[j] = bp[(size_t)(s * 16 + j) * HW];
            half8 B_h, B_l;
            #pragma unroll
            for (int j = 0; j < 8; ++j) {
                _Float16 h = (_Float16)x[j];
                B_h[j] = h;
                B_l[j] = (_Float16)(x[j] - (float)h);
            }
            acc = __builtin_amdgcn_mfma_f32_32x32x16_f16(A_h, B_h, acc, 0, 0, 0);
            acc = __builtin_amdgcn_mfma_f32_32x32x16_f16(A_h, B_l, acc, 0, 0, 0);
            acc = __builtin_amdgcn_mfma_f32_32x32x16_f16(A_l, B_h, acc, 0, 0, 0);
        }
        const int ccol = w * 32 + col;
        #pragma unroll
        for (int reg = 0; reg < 12; ++reg) {
            const int r = (reg & 3) + 8 * (reg >> 2) + 4 * kh;
            if (r < 22) sacc[r][ccol] = acc[reg];
        }
    }

    const int q    = tid & 127;
    const int role = tid >> 7;
    const int hw   = hwbase + q;
    const int vb   = n * 10 * HW + hw;
    float xu[10], xl[10], xv[10];
    #pragma unroll
    for (int i = 0; i < 10; ++i) xu[i] = xhu[vb + i * HW];
    #pragma unroll
    for (int i = 0; i < 10; ++i) xl[i] = xhl[vb + i * HW];
    #pragma unroll
    for (int i = 0; i < 10; ++i) xv[i] = xfg[vb + i * HW];

    __syncthreads();

    float au_s = att_b[0], al_s = att_b[1];
    #pragma unroll
    for (int i = 0; i < 10; ++i) {
        au_s = fmaf(att_w[i],      xu[i], au_s);
        al_s = fmaf(att_w[10 + i], xl[i], al_s);
    }
    const float au = sigm(au_s), al = sigm(al_s);

    if (role == 0) {
        float tt[10];
        #pragma unroll
        for (int o = 0; o < 10; ++o) {
            const float* wr = pdp_w1 + (10 + o) * 276;
            float s = sacc[10 + o][q];
            #pragma unroll
            for (int i = 0; i < 10; ++i) s = fmaf(wr[256 + i], xu[i], s);
            #pragma unroll
            for (int i = 0; i < 10; ++i) s = fmaf(wr[266 + i], xl[i], s);
            tt[o] = fmaxf(s, 0.f);
        }
        float dpl[10];
        #pragma unroll
        for (int o = 0; o < 10; ++o) {
            float s = 0.f;
            #pragma unroll
            for (int i = 0; i < 10; ++i) s = fmaf(pdp_w2[(10 + o) * 10 + i], tt[i], s);
            dpl[o] = fmaxf(s, 0.f);
        }
        float su = sacc[20][q] + dU_ab[0];
        #pragma unroll
        for (int i = 0; i < 10; ++i) su = fmaf(dU_aw[256 + i], xv[i], su);
        #pragma unroll
        for (int i = 0; i < 10; ++i) su = fmaf(dU_aw[266 + i], xu[i], su);
        const float attU = sigm(su);
        float xfh[10];
        #pragma unroll
        for (int o = 0; o < 10; ++o) {
            float a = 0.f;
            #pragma unroll
            for (int i = 0; i < 10; ++i) a = fmaf(dU_w[o * 10 + i], xv[i], a);
            xfh[o] = fmaxf(attU * a, 0.f);
        }
        float msg[10];
        #pragma unroll
        for (int i = 0; i < 10; ++i) msg[i] = 0.f;
        #pragma unroll
        for (int pp = 0; pp < 4; ++pp) {
            const float* xq = xpg + (size_t)(pp * 8 + n) * 10 * HW + hw;
            float v[10];
            #pragma unroll
            for (int i = 0; i < 10; ++i) v[i] = xq[i * HW];
            float s = cU_ab[pp];
            #pragma unroll
            for (int i = 0; i < 10; ++i) s = fmaf(cU_aw[pp * 10 + i], v[i], s);
            float ca = sigm(s);
            #pragma unroll
            for (int i = 0; i < 10; ++i) msg[i] = fmaf(ca, v[i], msg[i]);
        }
        float m[10];
        #pragma unroll
        for (int o = 0; o < 10; ++o) {
            float s = 0.f;
            #pragma unroll
            for (int i = 0; i < 10; ++i) s = fmaf(cU_w[o * 20 + i],      xu[i],  s);
            #pragma unroll
            for (int i = 0; i < 10; ++i) s = fmaf(cU_w[o * 20 + 10 + i], msg[i], s);
            m[o] = fmaxf(s, 0.f) + fmaf(dpl[o], al, xu[o] * au) + xfh[o];
        }
        #pragma unroll
        for (int o = 0; o < 10; ++o) {
            float gs = uU_gb[o], cs = 0.f;
            #pragma unroll
            for (int i = 0; i < 10; ++i) {
                gs = fmaf(uU_gw[o * 20 + i], xu[i], gs);
                cs = fmaf(uU_cw[o * 20 + i], xu[i], cs);
            }
            #pragma unroll
            for (int i = 0; i < 10; ++i) {
                gs = fmaf(uU_gw[o * 20 + 10 + i], m[i], gs);
                cs = fmaf(uU_cw[o * 20 + 10 + i], m[i], cs);
            }
            float g = sigm(gs), cd = fmaxf(cs, 0.f);
            out[vb + o * HW] = xu[o] * (1.f - g) + cd * g;
        }
        out[2621440 + n * HW + hw] = attU;
    } else {
        float tt[10];
        #pragma unroll
        for (int o = 0; o < 10; ++o) {
            const float* wr = pdp_w1 + o * 276;
            float s = sacc[o][q];
            #pragma unroll
            for (int i = 0; i < 10; ++i) s = fmaf(wr[256 + i], xu[i], s);
            #pragma unroll
            for (int i = 0; i < 10; ++i) s = fmaf(wr[266 + i], xl[i], s);
            tt[o] = fmaxf(s, 0.f);
        }
        float dpu[10];
        #pragma unroll
        for (int o = 0; o < 10; ++o) {
            float s = 0.f;
            #pragma unroll
            for (int i = 0; i < 10; ++i) s = fmaf(pdp_w2[o * 10 + i], tt[i], s);
            dpu[o] = fmaxf(s, 0.f);
        }
        float sl = sacc[21][q] + dL_ab[0];
        #pragma unroll
        for (int i = 0; i < 10; ++i) sl = fmaf(dL_aw[256 + i], xv[i], sl);
        #pragma unroll
        for (int i = 0; i < 10; ++i) sl = fmaf(dL_aw[266 + i], xl[i], sl);
        const float attL = sigm(sl);
        float xfh[10];
        #pragma unroll
        for (int o = 0; o < 10; ++o) {
            float a = 0.f;
            #pragma unroll
            for (int i = 0; i < 10; ++i) a = fmaf(dL_w[o * 10 + i], xv[i], a);
            xfh[o] = fmaxf(attL * a, 0.f);
        }
        float msg[10];
        #pragma unroll
        for (int i = 0; i < 10; ++i) msg[i] = 0.f;
        #pragma unroll
        for (int pp = 0; pp < 2; ++pp) {
            const float* xq = xpg + (size_t)((pp + 4) * 8 + n) * 10 * HW + hw;
            float v[10];
            #pragma unroll
            for (int i = 0; i < 10; ++i) v[i] = xq[i * HW];
            float s = cL_ab[pp];
            #pragma unroll
            for (int i = 0; i < 10; ++i) s = fmaf(cL_aw[pp * 10 + i], v[i], s);
            float ca = sigm(s);
            #pragma unroll
            for (int i = 0; i < 10; ++i) msg[i] = fmaf(ca, v[i], msg[i]);
        }
        float m[10];
        #pragma unroll
        for (int o = 0; o < 10; ++o) {
            float s = 0.f;
            #pragma unroll
            for (int i = 0; i < 10; ++i) s = fmaf(cL_w[o * 20 + i],      xl[i],  s);
            #pragma unroll
            for (int i = 0; i < 10; ++i) s = fmaf(cL_w[o * 20 + 10 + i], msg[i], s);
            m[o] = fmaxf(s, 0.f) + fmaf(dpu[o], au, xl[o] * al) + xfh[o];
        }
        #pragma unroll
        for (int o = 0; o < 10; ++o) {
            float gs = uL_gb[o], cs = 0.f;
            #pragma unroll
            for (int i = 0; i < 10; ++i) {
                gs = fmaf(uL_gw[o * 20 + i], xl[i], gs);
                cs = fmaf(uL_cw[o * 20 + i], xl[i], cs);
            }
            #pragma unroll
            for (int i = 0; i < 10; ++i) {
                gs = fmaf(uL_gw[o * 20 + 10 + i], m[i], gs);
                cs = fmaf(uL_cw[o * 20 + 10 + i], m[i], cs);
            }
            float g = sigm(gs), cd = fmaxf(cs, 0.f);
            out[1310720 + vb + o * HW] = xl[o] * (1.f - g) + cd * g;
        }
        out[2752512 + n * HW + hw] = attL;
    }
}

extern "C" void kernel_launch(void* const* d_in, const int* in_sizes, int n_in,
                              void* d_out, int out_size, void* d_ws, size_t ws_size,
                              hipStream_t stream) {
    (void)in_sizes; (void)n_in; (void)out_size;
    const float* hf   = (const float*)d_in[0];
    const float* xhu  = (const float*)d_in[1];
    const float* xhl  = (const float*)d_in[2];
    const float* xfg  = (const float*)d_in[3];
    const float* xpg  = (const float*)d_in[4];
    const float* w1   = (const float*)d_in[5];
    const float* w2   = (const float*)d_in[6];
    const float* aw   = (const float*)d_in[7];
    const float* ab   = (const float*)d_in[8];
    const float* cUaw = (const float*)d_in[9];
    const float* cUab = (const float*)d_in[10];
    const float* cUw  = (const float*)d_in[11];
    const float* cLaw = (const float*)d_in[12];
    const float* cLab = (const float*)d_in[13];
    const float* cLw  = (const float*)d_in[14];
    const float* dUaw = (const float*)d_in[15];
    const float* dUab = (const float*)d_in[16];
    const float* dUw  = (const float*)d_in[17];
    const float* dLaw = (const float*)d_in[18];
    const float* dLab = (const float*)d_in[19];
    const float* dLw  = (const float*)d_in[20];
    const float* uUgw = (const float*)d_in[21];
    const float* uUgb = (const float*)d_in[22];
    const float* uUcw = (const float*)d_in[23];
    const float* uLgw = (const float*)d_in[24];
    const float* uLgb = (const float*)d_in[25];
    const float* uLcw = (const float*)d_in[26];

    _Float16* apack = (_Float16*)d_ws;                       // 32 KB (R7-proven)
    const size_t need = 32768 + (size_t)22 * NPIX * sizeof(float);  // ~11.6 MB

    hipLaunchKernelGGL(prep_apack, dim3(32), dim3(256), 0, stream,
                       w1, dUaw, dLaw, apack);

    if (ws_size >= need) {
        float* gacc = (float*)((char*)d_ws + 32768);
        hipLaunchKernelGGL(gemm22, dim3(2048), dim3(256), 0, stream,
                           hf, (const _Float16*)apack, gacc);
        hipLaunchKernelGGL(half_graph_epi, dim3(2048), dim3(128), 0, stream,
            (const float*)gacc, xhu, xhl, xfg, xpg, w1, w2, aw, ab,
            cUaw, cUab, cUw, cLaw, cLab, cLw,
            dUaw, dUab, dUw, dLaw, dLab, dLw,
            uUgw, uUgb, uUcw, uLgw, uLgb, uLcw,
            (float*)d_out);
    } else {
        hipLaunchKernelGGL(half_graph_fused, dim3(1024), dim3(256), 0, stream,
            hf, xhu, xhl, xfg, xpg, w1, w2, aw, ab,
            cUaw, cUab, cUw, cLaw, cLab, cLw,
            dUaw, dUab, dUw, dLaw, dLab, dLw,
            uUgw, uUgb, uUcw, uLgw, uLgb, uLcw,
            (const _Float16*)apack,
            (float*)d_out);
    }
}

// Round 6
// 280.866 us; speedup vs baseline: 1.8650x; 1.0594x over previous
//
#include <hip/hip_runtime.h>
#include <stdint.h>

#define HW   16384          // 128*128
#define NPIX 131072         // 8 * HW

typedef __attribute__((ext_vector_type(8)))  _Float16 half8;
typedef __attribute__((ext_vector_type(16))) float    f32x16;

__device__ __forceinline__ float sigm(float x) { return 1.f / (1.f + __expf(-x)); }

// ---------------------------------------------------------------------------
// R12: fused kernel + in-block K-split -> 2x GEMM-phase occupancy.
//   R11 post-mortem: split path ran & passed (K-split GEMM indexing now
//   HW-verified) but device time ~100us vs fused 78.8 -> gacc round-trip +
//   epi reload overhead; fusion wins. R7 diagnosis stands: latency-bound
//   (VALU 18.6%, MFMA 3%, HBM 16%), 16 waves/CU = the structural cap, since
//   GEMM work = exactly 16 wave-jobs/CU at 32px x K256 per wave.
//   Fix: 8 waves/block (512 thr), each wave = 32px x K128 (half the job),
//   launch_bounds(512,8) -> 4 blocks/CU resident = 32 waves/CU in GEMM.
//   Waves 4-7 exit after sacc write; epi identical to R7 (waves 0-3).
//   Per-wave VGPR footprint unchanged (~48) -> fits the 64-VGPR cap.
// ---------------------------------------------------------------------------

// Pack padded 32x256 weight matrix (rows 0..19 = pdp_w1 hf-cols, row 20 =
// dU_aw[0:256], row 21 = dL_aw[0:256], rows 22..31 = 0) into lane-ordered
// split-f16 fragments: apack[s*512 + l*8 + j], s = K-step of 16.
__global__ __launch_bounds__(256) void prep_apack(
    const float* __restrict__ pdp_w1, const float* __restrict__ dU_aw,
    const float* __restrict__ dL_aw, _Float16* __restrict__ apack)
{
    int idx = blockIdx.x * 256 + threadIdx.x;      // [0, 8192)
    int s = idx >> 9, rem = idx & 511, l = rem >> 3, j = rem & 7;
    int o = l & 31, kh = l >> 5;
    int k = s * 16 + kh * 8 + j;
    float wv = 0.f;
    if (o < 20)       wv = pdp_w1[o * 276 + k];
    else if (o == 20) wv = dU_aw[k];
    else if (o == 21) wv = dL_aw[k];
    _Float16 h = (_Float16)wv;
    apack[idx]        = h;                          // A_hi
    apack[8192 + idx] = (_Float16)(wv - (float)h);  // A_lo (residual)
}

__global__ __launch_bounds__(512, 8) void half_graph_fused(
    const float* __restrict__ hf,  const float* __restrict__ xhu, const float* __restrict__ xhl,
    const float* __restrict__ xfg, const float* __restrict__ xpg,
    const float* __restrict__ pdp_w1, const float* __restrict__ pdp_w2,
    const float* __restrict__ att_w,  const float* __restrict__ att_b,
    const float* __restrict__ cU_aw, const float* __restrict__ cU_ab, const float* __restrict__ cU_w,
    const float* __restrict__ cL_aw, const float* __restrict__ cL_ab, const float* __restrict__ cL_w,
    const float* __restrict__ dU_aw, const float* __restrict__ dU_ab, const float* __restrict__ dU_w,
    const float* __restrict__ dL_aw, const float* __restrict__ dL_ab, const float* __restrict__ dL_w,
    const float* __restrict__ uU_gw, const float* __restrict__ uU_gb, const float* __restrict__ uU_cw,
    const float* __restrict__ uL_gw, const float* __restrict__ uL_gb, const float* __restrict__ uL_cw,
    const _Float16* __restrict__ apack,
    float* __restrict__ out)
{
    const int tid    = threadIdx.x;
    const int pxbase = blockIdx.x * 128;     // 128 px/block (128 | 16384)
    const int n      = pxbase >> 14;
    const int hwbase = pxbase & 16383;

    __shared__ float sacc[2][22][128];       // [khalf][row][px], 22.5 KB

    // ---- GEMM: 8 waves; wave w = px tile (w&3), K-half (w>>2), 8 steps ----
    {
        const int l     = tid & 63;
        const int w     = tid >> 6;
        const int col   = l & 31;
        const int kh    = l >> 5;
        const int ptile = w & 3;
        const int khalf = w >> 2;
        const float* bp = hf + ((size_t)(n * 256 + khalf * 128 + kh * 8)) * HW
                             + hwbase + ptile * 32 + col;
        const half8* ahp = (const half8*)apack + khalf * 512 + l;   // [8 steps][64]
        const half8* alp = ahp + 1024;
        f32x16 acc = {};
        #pragma unroll 2
        for (int s = 0; s < 8; ++s) {
            half8 A_h = ahp[s * 64];
            half8 A_l = alp[s * 64];
            float x[8];
            #pragma unroll
            for (int j = 0; j < 8; ++j) x[j] = bp[(size_t)(s * 16 + j) * HW];  // coalesced
            half8 B_h, B_l;
            #pragma unroll
            for (int j = 0; j < 8; ++j) {          // split f32 -> f16 hi + lo
                _Float16 h = (_Float16)x[j];
                B_h[j] = h;
                B_l[j] = (_Float16)(x[j] - (float)h);
            }
            acc = __builtin_amdgcn_mfma_f32_32x32x16_f16(A_h, B_h, acc, 0, 0, 0);
            acc = __builtin_amdgcn_mfma_f32_32x32x16_f16(A_h, B_l, acc, 0, 0, 0);
            acc = __builtin_amdgcn_mfma_f32_32x32x16_f16(A_l, B_h, acc, 0, 0, 0);
        }
        // C/D: col=lane&31, row=(reg&3)+8*(reg>>2)+4*(lane>>5)  [R7-verified]
        const int ccol = ptile * 32 + col;
        #pragma unroll
        for (int reg = 0; reg < 12; ++reg) {
            const int r = (reg & 3) + 8 * (reg >> 2) + 4 * kh;
            if (r < 22) sacc[khalf][r][ccol] = acc[reg];
        }
    }

    // per-pixel small vectors: issue before the barrier (epi waves only)
    const int q    = tid & 127;              // pixel within block
    const int role = tid >> 7;               // 0,1 valid; waves 4-7 exit below
    const int hw   = hwbase + q;
    const int vb   = n * 10 * HW + hw;
    float xu[10], xl[10], xv[10];
    if (tid < 256) {
        #pragma unroll
        for (int i = 0; i < 10; ++i) xu[i] = xhu[vb + i * HW];
        #pragma unroll
        for (int i = 0; i < 10; ++i) xl[i] = xhl[vb + i * HW];
        #pragma unroll
        for (int i = 0; i < 10; ++i) xv[i] = xfg[vb + i * HW];
    }

    __syncthreads();
    if (tid >= 256) return;                  // GEMM-only waves done

    // gates (both halves need both)
    float au_s = att_b[0], al_s = att_b[1];
    #pragma unroll
    for (int i = 0; i < 10; ++i) {
        au_s = fmaf(att_w[i],      xu[i], au_s);
        al_s = fmaf(att_w[10 + i], xl[i], al_s);
    }
    const float au = sigm(au_s), al = sigm(al_s);

    if (role == 0) {
        // ------------------------------ U half ------------------------------
        float tt[10];                        // t rows 10..19 (feed dp_l)
        #pragma unroll
        for (int o = 0; o < 10; ++o) {
            const float* wr = pdp_w1 + (10 + o) * 276;
            float s = sacc[0][10 + o][q] + sacc[1][10 + o][q];
            #pragma unroll
            for (int i = 0; i < 10; ++i) s = fmaf(wr[256 + i], xu[i], s);
            #pragma unroll
            for (int i = 0; i < 10; ++i) s = fmaf(wr[266 + i], xl[i], s);
            tt[o] = fmaxf(s, 0.f);
        }
        float dpl[10];
        #pragma unroll
        for (int o = 0; o < 10; ++o) {
            float s = 0.f;
            #pragma unroll
            for (int i = 0; i < 10; ++i) s = fmaf(pdp_w2[(10 + o) * 10 + i], tt[i], s);
            dpl[o] = fmaxf(s, 0.f);
        }
        float su = sacc[0][20][q] + sacc[1][20][q] + dU_ab[0];
        #pragma unroll
        for (int i = 0; i < 10; ++i) su = fmaf(dU_aw[256 + i], xv[i], su);
        #pragma unroll
        for (int i = 0; i < 10; ++i) su = fmaf(dU_aw[266 + i], xu[i], su);
        const float attU = sigm(su);
        float xfh[10];
        #pragma unroll
        for (int o = 0; o < 10; ++o) {
            float a = 0.f;
            #pragma unroll
            for (int i = 0; i < 10; ++i) a = fmaf(dU_w[o * 10 + i], xv[i], a);
            xfh[o] = fmaxf(attU * a, 0.f);
        }
        float msg[10];
        #pragma unroll
        for (int i = 0; i < 10; ++i) msg[i] = 0.f;
        #pragma unroll
        for (int pp = 0; pp < 4; ++pp) {
            const float* xq = xpg + (size_t)(pp * 8 + n) * 10 * HW + hw;
            float v[10];
            #pragma unroll
            for (int i = 0; i < 10; ++i) v[i] = xq[i * HW];
            float s = cU_ab[pp];
            #pragma unroll
            for (int i = 0; i < 10; ++i) s = fmaf(cU_aw[pp * 10 + i], v[i], s);
            float ca = sigm(s);
            #pragma unroll
            for (int i = 0; i < 10; ++i) msg[i] = fmaf(ca, v[i], msg[i]);
        }
        float m[10];
        #pragma unroll
        for (int o = 0; o < 10; ++o) {
            float s = 0.f;
            #pragma unroll
            for (int i = 0; i < 10; ++i) s = fmaf(cU_w[o * 20 + i],      xu[i],  s);
            #pragma unroll
            for (int i = 0; i < 10; ++i) s = fmaf(cU_w[o * 20 + 10 + i], msg[i], s);
            m[o] = fmaxf(s, 0.f) + fmaf(dpl[o], al, xu[o] * au) + xfh[o];
        }
        #pragma unroll
        for (int o = 0; o < 10; ++o) {
            float gs = uU_gb[o], cs = 0.f;
            #pragma unroll
            for (int i = 0; i < 10; ++i) {
                gs = fmaf(uU_gw[o * 20 + i], xu[i], gs);
                cs = fmaf(uU_cw[o * 20 + i], xu[i], cs);
            }
            #pragma unroll
            for (int i = 0; i < 10; ++i) {
                gs = fmaf(uU_gw[o * 20 + 10 + i], m[i], gs);
                cs = fmaf(uU_cw[o * 20 + 10 + i], m[i], cs);
            }
            float g = sigm(gs), cd = fmaxf(cs, 0.f);
            out[vb + o * HW] = xu[o] * (1.f - g) + cd * g;
        }
        out[2621440 + n * HW + hw] = attU;
    } else {
        // ------------------------------ L half ------------------------------
        float tt[10];                        // t rows 0..9 (feed dp_u)
        #pragma unroll
        for (int o = 0; o < 10; ++o) {
            const float* wr = pdp_w1 + o * 276;
            float s = sacc[0][o][q] + sacc[1][o][q];
            #pragma unroll
            for (int i = 0; i < 10; ++i) s = fmaf(wr[256 + i], xu[i], s);
            #pragma unroll
            for (int i = 0; i < 10; ++i) s = fmaf(wr[266 + i], xl[i], s);
            tt[o] = fmaxf(s, 0.f);
        }
        float dpu[10];
        #pragma unroll
        for (int o = 0; o < 10; ++o) {
            float s = 0.f;
            #pragma unroll
            for (int i = 0; i < 10; ++i) s = fmaf(pdp_w2[o * 10 + i], tt[i], s);
            dpu[o] = fmaxf(s, 0.f);
        }
        float sl = sacc[0][21][q] + sacc[1][21][q] + dL_ab[0];
        #pragma unroll
        for (int i = 0; i < 10; ++i) sl = fmaf(dL_aw[256 + i], xv[i], sl);
        #pragma unroll
        for (int i = 0; i < 10; ++i) sl = fmaf(dL_aw[266 + i], xl[i], sl);
        const float attL = sigm(sl);
        float xfh[10];
        #pragma unroll
        for (int o = 0; o < 10; ++o) {
            float a = 0.f;
            #pragma unroll
            for (int i = 0; i < 10; ++i) a = fmaf(dL_w[o * 10 + i], xv[i], a);
            xfh[o] = fmaxf(attL * a, 0.f);
        }
        float msg[10];
        #pragma unroll
        for (int i = 0; i < 10; ++i) msg[i] = 0.f;
        #pragma unroll
        for (int pp = 0; pp < 2; ++pp) {
            const float* xq = xpg + (size_t)((pp + 4) * 8 + n) * 10 * HW + hw;
            float v[10];
            #pragma unroll
            for (int i = 0; i < 10; ++i) v[i] = xq[i * HW];
            float s = cL_ab[pp];
            #pragma unroll
            for (int i = 0; i < 10; ++i) s = fmaf(cL_aw[pp * 10 + i], v[i], s);
            float ca = sigm(s);
            #pragma unroll
            for (int i = 0; i < 10; ++i) msg[i] = fmaf(ca, v[i], msg[i]);
        }
        float m[10];
        #pragma unroll
        for (int o = 0; o < 10; ++o) {
            float s = 0.f;
            #pragma unroll
            for (int i = 0; i < 10; ++i) s = fmaf(cL_w[o * 20 + i],      xl[i],  s);
            #pragma unroll
            for (int i = 0; i < 10; ++i) s = fmaf(cL_w[o * 20 + 10 + i], msg[i], s);
            m[o] = fmaxf(s, 0.f) + fmaf(dpu[o], au, xl[o] * al) + xfh[o];
        }
        #pragma unroll
        for (int o = 0; o < 10; ++o) {
            float gs = uL_gb[o], cs = 0.f;
            #pragma unroll
            for (int i = 0; i < 10; ++i) {
                gs = fmaf(uL_gw[o * 20 + i], xl[i], gs);
                cs = fmaf(uL_cw[o * 20 + i], xl[i], cs);
            }
            #pragma unroll
            for (int i = 0; i < 10; ++i) {
                gs = fmaf(uL_gw[o * 20 + 10 + i], m[i], gs);
                cs = fmaf(uL_cw[o * 20 + 10 + i], m[i], cs);
            }
            float g = sigm(gs), cd = fmaxf(cs, 0.f);
            out[1310720 + vb + o * HW] = xl[o] * (1.f - g) + cd * g;
        }
        out[2752512 + n * HW + hw] = attL;
    }
}

extern "C" void kernel_launch(void* const* d_in, const int* in_sizes, int n_in,
                              void* d_out, int out_size, void* d_ws, size_t ws_size,
                              hipStream_t stream) {
    (void)in_sizes; (void)n_in; (void)out_size; (void)ws_size;
    const float* hf   = (const float*)d_in[0];
    const float* xhu  = (const float*)d_in[1];
    const float* xhl  = (const float*)d_in[2];
    const float* xfg  = (const float*)d_in[3];
    const float* xpg  = (const float*)d_in[4];
    const float* w1   = (const float*)d_in[5];
    const float* w2   = (const float*)d_in[6];
    const float* aw   = (const float*)d_in[7];
    const float* ab   = (const float*)d_in[8];
    const float* cUaw = (const float*)d_in[9];
    const float* cUab = (const float*)d_in[10];
    const float* cUw  = (const float*)d_in[11];
    const float* cLaw = (const float*)d_in[12];
    const float* cLab = (const float*)d_in[13];
    const float* cLw  = (const float*)d_in[14];
    const float* dUaw = (const float*)d_in[15];
    const float* dUab = (const float*)d_in[16];
    const float* dUw  = (const float*)d_in[17];
    const float* dLaw = (const float*)d_in[18];
    const float* dLab = (const float*)d_in[19];
    const float* dLw  = (const float*)d_in[20];
    const float* uUgw = (const float*)d_in[21];
    const float* uUgb = (const float*)d_in[22];
    const float* uUcw = (const float*)d_in[23];
    const float* uLgw = (const float*)d_in[24];
    const float* uLgb = (const float*)d_in[25];
    const float* uLcw = (const float*)d_in[26];

    _Float16* apack = (_Float16*)d_ws;       // 32 KB: [16][64][8] hi + lo

    hipLaunchKernelGGL(prep_apack, dim3(32), dim3(256), 0, stream,
                       w1, dUaw, dLaw, apack);
    hipLaunchKernelGGL(half_graph_fused, dim3(1024), dim3(512), 0, stream,
        hf, xhu, xhl, xfg, xpg, w1, w2, aw, ab,
        cUaw, cUab, cUw, cLaw, cLab, cLw,
        dUaw, dUab, dUw, dLaw, dLab, dLw,
        uUgw, uUgb, uUcw, uLgw, uLgb, uLcw,
        (const _Float16*)apack,
        (float*)d_out);
}